// Round 1
// baseline (1062.402 us; speedup 1.0000x reference)
//
#include <hip/hip_runtime.h>

#define R_ 64
#define C_ 2048
#define E_ 512
#define H_ 8
#define D_ 64

constexpr int CE = C_ * E_;                 // 1,048,576
constexpr long long OUT_ELEMS = 67108864LL; // R*C*E
// attn region: 8*2048*2048 = 33,554,432 floats at d_out + OUT_ELEMS

typedef __attribute__((ext_vector_type(8))) short bf16x8;
typedef __attribute__((ext_vector_type(4))) short bf16x4;
typedef __attribute__((ext_vector_type(4))) float f32x4;

__device__ __forceinline__ unsigned short f2bf(float f) {
    union { float f; unsigned u; } v; v.f = f;
    unsigned r = v.u + 0x7FFFu + ((v.u >> 16) & 1u);  // RNE
    return (unsigned short)(r >> 16);
}

// ---------------------------------------------------------------- mean over R
__global__ __launch_bounds__(256) void mean_x(const float4* __restrict__ x4,
                                              float4* __restrict__ xbar4) {
    int idx = blockIdx.x * 256 + threadIdx.x;   // CE/4 = 262144 total
    float4 a = x4[idx];
    for (int r = 1; r < R_; ++r) {
        float4 t = x4[(size_t)r * (CE / 4) + idx];
        a.x += t.x; a.y += t.y; a.z += t.z; a.w += t.w;
    }
    a.x *= 0.015625f; a.y *= 0.015625f; a.z *= 0.015625f; a.w *= 0.015625f;
    xbar4[idx] = a;
}

// ------------------------------------------- generic fp32 NT tile GEMM (64x64)
// C[m][n] = sum_k A[m][k]*B[n][k] + bias ; grid.x = N/64, grid.y = M/64
__global__ __launch_bounds__(256) void gemm_nt(const float* __restrict__ A, int lda,
                                               const float* __restrict__ B, int ldb,
                                               float* __restrict__ Cmat, int ldc, int K,
                                               const float* __restrict__ bias, int biasPerM) {
    __shared__ float As[64][65];
    __shared__ float Bs[64][65];
    int m0 = blockIdx.y * 64, n0 = blockIdx.x * 64;
    int t = threadIdx.x, tx = t & 15, ty = t >> 4;
    float acc[4][4] = {};
    for (int k0 = 0; k0 < K; k0 += 64) {
        #pragma unroll
        for (int i = 0; i < 4; ++i) {
            int r = ty + i * 16, cc = tx * 4;
            float4 av = *(const float4*)(A + (size_t)(m0 + r) * lda + k0 + cc);
            As[r][cc] = av.x; As[r][cc + 1] = av.y; As[r][cc + 2] = av.z; As[r][cc + 3] = av.w;
            float4 bv = *(const float4*)(B + (size_t)(n0 + r) * ldb + k0 + cc);
            Bs[r][cc] = bv.x; Bs[r][cc + 1] = bv.y; Bs[r][cc + 2] = bv.z; Bs[r][cc + 3] = bv.w;
        }
        __syncthreads();
        for (int kk = 0; kk < 64; ++kk) {
            float a[4], b[4];
            #pragma unroll
            for (int i = 0; i < 4; ++i) a[i] = As[ty + 16 * i][kk];
            #pragma unroll
            for (int l = 0; l < 4; ++l) b[l] = Bs[tx + 16 * l][kk];
            #pragma unroll
            for (int i = 0; i < 4; ++i)
                #pragma unroll
                for (int l = 0; l < 4; ++l) acc[i][l] += a[i] * b[l];
        }
        __syncthreads();
    }
    #pragma unroll
    for (int i = 0; i < 4; ++i)
        #pragma unroll
        for (int l = 0; l < 4; ++l) {
            int m = m0 + ty + 16 * i, n = n0 + tx + 16 * l;
            Cmat[(size_t)m * ldc + n] = acc[i][l] + (biasPerM ? bias[m] : bias[n]);
        }
}

// ---------------------------------------------------------- softmax q (over D)
__global__ __launch_bounds__(256) void softmax_q(float* __restrict__ q) {
    int t = threadIdx.x;
    int chunk = blockIdx.x * 4 + (t >> 6);  // (c*8+h), rows of 64 contiguous
    int lane = t & 63;
    float* p = q + (size_t)chunk * 64;
    float v = p[lane];
    float m = v;
    for (int o = 32; o; o >>= 1) m = fmaxf(m, __shfl_xor(m, o));
    float e = expf(v - m);
    float s = e;
    for (int o = 32; o; o >>= 1) s += __shfl_xor(s, o);
    p[lane] = e / s * 0.125f;  // * D^-0.5
}

// ------------------------------------------- softmax k (over C), emit bf16 too
__global__ __launch_bounds__(256) void softmax_k(float* __restrict__ kT,
                                                 unsigned short* __restrict__ kbf) {
    __shared__ float red[256];
    int j = blockIdx.x, t = threadIdx.x;
    float* row = kT + (size_t)j * C_;
    float vals[8];
    float mx = -1e30f;
    #pragma unroll
    for (int i = 0; i < 8; ++i) { vals[i] = row[t + 256 * i]; mx = fmaxf(mx, vals[i]); }
    red[t] = mx; __syncthreads();
    for (int s = 128; s; s >>= 1) { if (t < s) red[t] = fmaxf(red[t], red[t + s]); __syncthreads(); }
    mx = red[0]; __syncthreads();
    float sum = 0.f;
    #pragma unroll
    for (int i = 0; i < 8; ++i) { vals[i] = expf(vals[i] - mx); sum += vals[i]; }
    red[t] = sum; __syncthreads();
    for (int s = 128; s; s >>= 1) { if (t < s) red[t] += red[t + s]; __syncthreads(); }
    float inv = 1.0f / red[0];
    #pragma unroll
    for (int i = 0; i < 8; ++i) {
        float v = vals[i] * inv;
        row[t + 256 * i] = v;
        kbf[(size_t)j * C_ + t + 256 * i] = f2bf(v);
    }
}

// --------------------- T[b] = ksmT(bf16) @ x[b] : MFMA bf16, M=N=512, K=2048
__global__ __launch_bounds__(256) void t_gemm(const unsigned short* __restrict__ Abf,
                                              const float* __restrict__ x,
                                              float* __restrict__ Tout) {
    __shared__ __align__(16) unsigned short As[64 * 40];  // row stride 40 shorts (80B)
    __shared__ __align__(16) unsigned short Bt[64 * 40];  // x-tile transposed -> [n][k]
    const int b = blockIdx.z;
    const float* xb = x + (size_t)b * CE;
    const int m0 = blockIdx.y * 64, n0 = blockIdx.x * 64;
    const int t = threadIdx.x;
    const int lane = t & 63, wave = t >> 6;
    const int wm = (wave >> 1) * 32, wn = (wave & 1) * 32;
    const int l15 = lane & 15, quad = lane >> 4;
    f32x4 acc[2][2];
    #pragma unroll
    for (int i = 0; i < 2; ++i)
        #pragma unroll
        for (int j = 0; j < 2; ++j) acc[i][j] = (f32x4){0.f, 0.f, 0.f, 0.f};

    const int arow = t >> 2, aseg = (t & 3) * 8;  // A: 64 rows x 32 bf16
    const int bn = t & 63, bkb = (t >> 6) * 4;    // B: col n, k-quads

    for (int k0 = 0; k0 < C_; k0 += 32) {
        // stage A tile (bf16 rows, contiguous k)
        *(bf16x8*)(&As[arow * 40 + aseg]) =
            *(const bf16x8*)(Abf + (size_t)(m0 + arow) * C_ + k0 + aseg);
        // stage B tile transposed with fp32->bf16 cvt
        #pragma unroll
        for (int half = 0; half < 2; ++half) {
            int k = bkb + half * 16;
            const float* xp = xb + (size_t)(k0 + k) * E_ + n0 + bn;
            bf16x4 u;
            u.x = (short)f2bf(xp[0]);
            u.y = (short)f2bf(xp[E_]);
            u.z = (short)f2bf(xp[2 * E_]);
            u.w = (short)f2bf(xp[3 * E_]);
            *(bf16x4*)(&Bt[bn * 40 + k]) = u;
        }
        __syncthreads();
        bf16x8 af[2], bfr[2];
        #pragma unroll
        for (int mi = 0; mi < 2; ++mi)
            af[mi] = *(const bf16x8*)(&As[(wm + mi * 16 + l15) * 40 + quad * 8]);
        #pragma unroll
        for (int ni = 0; ni < 2; ++ni)
            bfr[ni] = *(const bf16x8*)(&Bt[(wn + ni * 16 + l15) * 40 + quad * 8]);
        #pragma unroll
        for (int mi = 0; mi < 2; ++mi)
            #pragma unroll
            for (int ni = 0; ni < 2; ++ni)
                acc[mi][ni] = __builtin_amdgcn_mfma_f32_16x16x32_bf16(
                    af[mi], bfr[ni], acc[mi][ni], 0, 0, 0);
        __syncthreads();
    }
    float* To = Tout + (size_t)b * 262144;
    #pragma unroll
    for (int mi = 0; mi < 2; ++mi)
        #pragma unroll
        for (int ni = 0; ni < 2; ++ni)
            #pragma unroll
            for (int r = 0; r < 4; ++r) {
                int m = m0 + wm + mi * 16 + quad * 4 + r;  // D row = quad*4+reg
                int n = n0 + wn + ni * 16 + l15;           // D col = lane&15
                To[(size_t)m * 512 + n] = acc[mi][ni][r];
            }
}

// ------------------- ctx[b,h] = T[b,h] @ Wv_h^T + bv  (64x64 out, K=512, NT)
__global__ __launch_bounds__(256) void ctx_kernel(const float* __restrict__ T,
                                                  const float* __restrict__ Wv,
                                                  const float* __restrict__ bv,
                                                  float* __restrict__ ctx) {
    __shared__ float As[64][65];
    __shared__ float Bs[64][65];
    int z = blockIdx.x, b = z >> 3, h = z & 7;
    const float* A = T + (size_t)b * 262144 + (size_t)h * 64 * 512;  // rows d
    const float* B = Wv + (size_t)h * 64 * 512;                      // rows e'
    int t = threadIdx.x, tx = t & 15, ty = t >> 4;
    float acc[4][4] = {};
    for (int k0 = 0; k0 < 512; k0 += 64) {
        #pragma unroll
        for (int i = 0; i < 4; ++i) {
            int r = ty + i * 16, cc = tx * 4;
            float4 av = *(const float4*)(A + (size_t)r * 512 + k0 + cc);
            As[r][cc] = av.x; As[r][cc + 1] = av.y; As[r][cc + 2] = av.z; As[r][cc + 3] = av.w;
            float4 bvv = *(const float4*)(B + (size_t)r * 512 + k0 + cc);
            Bs[r][cc] = bvv.x; Bs[r][cc + 1] = bvv.y; Bs[r][cc + 2] = bvv.z; Bs[r][cc + 3] = bvv.w;
        }
        __syncthreads();
        for (int kk = 0; kk < 64; ++kk) {
            float a[4], bb[4];
            #pragma unroll
            for (int i = 0; i < 4; ++i) a[i] = As[ty + 16 * i][kk];
            #pragma unroll
            for (int l = 0; l < 4; ++l) bb[l] = Bs[tx + 16 * l][kk];
            #pragma unroll
            for (int i = 0; i < 4; ++i)
                #pragma unroll
                for (int l = 0; l < 4; ++l) acc[i][l] += a[i] * bb[l];
        }
        __syncthreads();
    }
    #pragma unroll
    for (int i = 0; i < 4; ++i)
        #pragma unroll
        for (int l = 0; l < 4; ++l) {
            int d = ty + 16 * i, e = tx + 16 * l;
            ctx[(size_t)z * 4096 + d * 64 + e] = acc[i][l] + bv[h * 64 + e];
        }
}

// ---------------- out[b, n, h*64+e'] = q[n, h*64+d] @ ctx[b,h][d][e']  (K=64)
__global__ __launch_bounds__(256) void out_kernel(const float* __restrict__ q,
                                                  const float* __restrict__ ctx,
                                                  float* __restrict__ outp) {
    __shared__ float As[64][65];
    __shared__ float Bs[64][65];
    int z = blockIdx.z, b = z >> 3, h = z & 7;
    int m0 = blockIdx.y * 64;
    int t = threadIdx.x, tx = t & 15, ty = t >> 4;
    #pragma unroll
    for (int i = 0; i < 4; ++i) {
        int r = ty + i * 16, cc = tx * 4;
        float4 av = *(const float4*)(q + (size_t)(m0 + r) * 512 + h * 64 + cc);
        As[r][cc] = av.x; As[r][cc + 1] = av.y; As[r][cc + 2] = av.z; As[r][cc + 3] = av.w;
        float4 bvv = *(const float4*)(ctx + (size_t)z * 4096 + r * 64 + cc);
        Bs[r][cc] = bvv.x; Bs[r][cc + 1] = bvv.y; Bs[r][cc + 2] = bvv.z; Bs[r][cc + 3] = bvv.w;
    }
    __syncthreads();
    float acc[4][4] = {};
    for (int kk = 0; kk < 64; ++kk) {
        float a[4], bb[4];
        #pragma unroll
        for (int i = 0; i < 4; ++i) a[i] = As[ty + 16 * i][kk];
        #pragma unroll
        for (int l = 0; l < 4; ++l) bb[l] = Bs[kk][tx + 16 * l];
        #pragma unroll
        for (int i = 0; i < 4; ++i)
            #pragma unroll
            for (int l = 0; l < 4; ++l) acc[i][l] += a[i] * bb[l];
    }
    #pragma unroll
    for (int i = 0; i < 4; ++i)
        #pragma unroll
        for (int l = 0; l < 4; ++l) {
            int n = m0 + ty + 16 * i, e = tx + 16 * l;
            outp[((size_t)b * C_ + n) * E_ + h * 64 + e] = acc[i][l];
        }
}

// ----------------------------- attn[h][n][m] = q[n,h:] . kT[h:][m]  (K=64, NN)
__global__ __launch_bounds__(256) void attn_kernel(const float* __restrict__ q,
                                                   const float* __restrict__ kT,
                                                   float* __restrict__ attn) {
    __shared__ float As[64][65];
    __shared__ float Bs[64][65];
    int h = blockIdx.z;
    int n0 = blockIdx.y * 64, m0 = blockIdx.x * 64;
    int t = threadIdx.x, tx = t & 15, ty = t >> 4;
    #pragma unroll
    for (int i = 0; i < 4; ++i) {
        int r = ty + i * 16, cc = tx * 4;
        float4 av = *(const float4*)(q + (size_t)(n0 + r) * 512 + h * 64 + cc);
        As[r][cc] = av.x; As[r][cc + 1] = av.y; As[r][cc + 2] = av.z; As[r][cc + 3] = av.w;
        float4 bvv = *(const float4*)(kT + (size_t)(h * 64 + r) * C_ + m0 + cc);
        Bs[r][cc] = bvv.x; Bs[r][cc + 1] = bvv.y; Bs[r][cc + 2] = bvv.z; Bs[r][cc + 3] = bvv.w;
    }
    __syncthreads();
    float acc[4][4] = {};
    for (int kk = 0; kk < 64; ++kk) {
        float a[4], bb[4];
        #pragma unroll
        for (int i = 0; i < 4; ++i) a[i] = As[ty + 16 * i][kk];
        #pragma unroll
        for (int l = 0; l < 4; ++l) bb[l] = Bs[kk][tx + 16 * l];
        #pragma unroll
        for (int i = 0; i < 4; ++i)
            #pragma unroll
            for (int l = 0; l < 4; ++l) acc[i][l] += a[i] * bb[l];
    }
    #pragma unroll
    for (int i = 0; i < 4; ++i)
        #pragma unroll
        for (int l = 0; l < 4; ++l) {
            int n = n0 + ty + 16 * i, m = m0 + tx + 16 * l;
            attn[(size_t)h * C_ * C_ + (size_t)n * C_ + m] = acc[i][l];
        }
}

extern "C" void kernel_launch(void* const* d_in, const int* in_sizes, int n_in,
                              void* d_out, int out_size, void* d_ws, size_t ws_size,
                              hipStream_t stream) {
    const float* x  = (const float*)d_in[0];
    const float* Wq = (const float*)d_in[1];
    const float* bq = (const float*)d_in[2];
    const float* Wk = (const float*)d_in[3];
    const float* bk = (const float*)d_in[4];
    const float* Wv = (const float*)d_in[5];
    const float* bv = (const float*)d_in[6];
    float* out = (float*)d_out;

    float* ws = (float*)d_ws;
    float* xbar = ws;                                    // 1,048,576 fl
    float* qsm  = ws + 1048576;                          // 1,048,576 fl
    float* kT   = ws + 2097152;                          // 1,048,576 fl [E][C]
    unsigned short* kbf = (unsigned short*)(ws + 3145728);  // 1,048,576 us
    float* ctx  = ws + 3670016;                          // 2,097,152 fl
    float* Tb   = out + OUT_ELEMS;                       // T parked in attn region (67MB<134MB)

    mean_x<<<1024, 256, 0, stream>>>((const float4*)x, (float4*)xbar);
    // qpre[c][j] = xbar @ Wq^T + bq
    gemm_nt<<<dim3(8, 32), 256, 0, stream>>>(xbar, 512, Wq, 512, qsm, 512, 512, bq, 0);
    // kpreT[j][c] = Wk @ xbar^T + bk (written transposed)
    gemm_nt<<<dim3(32, 8), 256, 0, stream>>>(Wk, 512, xbar, 512, kT, 2048, 512, bk, 1);
    softmax_q<<<4096, 256, 0, stream>>>(qsm);
    softmax_k<<<512, 256, 0, stream>>>(kT, kbf);
    t_gemm<<<dim3(8, 8, 64), 256, 0, stream>>>(kbf, x, Tb);
    ctx_kernel<<<512, 256, 0, stream>>>(Tb, Wv, bv, ctx);
    out_kernel<<<dim3(1, 32, 512), 256, 0, stream>>>(qsm, ctx, out);
    attn_kernel<<<dim3(32, 32, 8), 256, 0, stream>>>(qsm, kT, out + OUT_ELEMS);
}

// Round 2
// 1034.363 us; speedup vs baseline: 1.0271x; 1.0271x over previous
//
#include <hip/hip_runtime.h>

#define R_ 64
#define C_ 2048
#define E_ 512
#define H_ 8
#define D_ 64

constexpr int CE = C_ * E_;                 // 1,048,576
constexpr long long OUT_ELEMS = 67108864LL; // R*C*E floats
// d_out layout: [0, OUT_ELEMS) = out ; [OUT_ELEMS, +33554432) = attn
// scratch aliasing: xT(bf16, 67.1M shorts = 33.5M floats) lives in out region
// (dead before out_kernel); T (16.8M floats) lives in attn region (dead
// before attn_kernel).

typedef __attribute__((ext_vector_type(8))) short bf16x8;
typedef __attribute__((ext_vector_type(4))) float f32x4;

__device__ __forceinline__ unsigned short f2bf(float f) {
    union { float f; unsigned u; } v; v.f = f;
    unsigned r = v.u + 0x7FFFu + ((v.u >> 16) & 1u);  // RNE
    return (unsigned short)(r >> 16);
}

typedef __attribute__((address_space(1))) unsigned char glob_t;
typedef __attribute__((address_space(3))) unsigned char lds_t;
__device__ __forceinline__ void gld_lds16(const unsigned short* g, unsigned short* l) {
    __builtin_amdgcn_global_load_lds((const glob_t*)g, (lds_t*)l, 16, 0, 0);
}

// ---------------- prep: xbar = mean_r x ; xT[b][e][c] = bf16(x[b][c][e]) ----
__global__ __launch_bounds__(256) void prep(const float* __restrict__ x,
                                            float* __restrict__ xbar,
                                            unsigned short* __restrict__ xT) {
    __shared__ float Ts[64][65];
    int c0 = blockIdx.x * 64, e0 = blockIdx.y * 64;
    int t = threadIdx.x;
    int r = t >> 2;            // 0..63 (c-local)
    int cs = (t & 3) * 16;     // e-local base, 16 floats
    float acc[16] = {};
    for (int b = 0; b < 64; ++b) {
        const float* xp = x + ((size_t)b * C_ + c0 + r) * E_ + e0 + cs;
        float vv[16];
        float4 v0 = *(const float4*)(xp);
        float4 v1 = *(const float4*)(xp + 4);
        float4 v2 = *(const float4*)(xp + 8);
        float4 v3 = *(const float4*)(xp + 12);
        vv[0]=v0.x; vv[1]=v0.y; vv[2]=v0.z; vv[3]=v0.w;
        vv[4]=v1.x; vv[5]=v1.y; vv[6]=v1.z; vv[7]=v1.w;
        vv[8]=v2.x; vv[9]=v2.y; vv[10]=v2.z; vv[11]=v2.w;
        vv[12]=v3.x; vv[13]=v3.y; vv[14]=v3.z; vv[15]=v3.w;
        #pragma unroll
        for (int i = 0; i < 16; ++i) acc[i] += vv[i];
        __syncthreads();   // protect prior iteration's Ts reads
        #pragma unroll
        for (int i = 0; i < 16; ++i) Ts[cs + i][r] = vv[i];  // transpose into LDS
        __syncthreads();
        // read back rows of transposed tile: e-row j, c cols cs..cs+15
        unsigned short ob[16];
        #pragma unroll
        for (int i = 0; i < 16; ++i) ob[i] = f2bf(Ts[r][cs + i]);
        unsigned short* op = xT + ((size_t)b * E_ + e0 + r) * C_ + c0 + cs;
        *(bf16x8*)(op)     = *(bf16x8*)(ob);
        *(bf16x8*)(op + 8) = *(bf16x8*)(ob + 8);
    }
    float* xb = xbar + (size_t)(c0 + r) * E_ + e0 + cs;
    #pragma unroll
    for (int i = 0; i < 16; ++i) xb[i] = acc[i] * 0.015625f;
}

// -------- fp32 NT GEMM 64x64 tiles: C[m][n] = sum_k A[m][k]*B[n][k] + bias --
__global__ __launch_bounds__(256) void gemm_nt(const float* __restrict__ A, int lda,
                                               const float* __restrict__ B, int ldb,
                                               float* __restrict__ Cmat, int ldc, int K,
                                               const float* __restrict__ bias, int biasPerM) {
    __shared__ float As[64][65];
    __shared__ float Bs[64][65];   // stored transposed: Bs[k][n]
    int m0 = blockIdx.y * 64, n0 = blockIdx.x * 64;
    int t = threadIdx.x, tx = t & 15, ty = t >> 4;
    float acc[4][4] = {};
    for (int k0 = 0; k0 < K; k0 += 64) {
        #pragma unroll
        for (int i = 0; i < 4; ++i) {
            int rr = ty + i * 16, cc = tx * 4;
            float4 av = *(const float4*)(A + (size_t)(m0 + rr) * lda + k0 + cc);
            As[rr][cc] = av.x; As[rr][cc + 1] = av.y; As[rr][cc + 2] = av.z; As[rr][cc + 3] = av.w;
            float4 bv = *(const float4*)(B + (size_t)(n0 + rr) * ldb + k0 + cc);
            Bs[cc][rr] = bv.x; Bs[cc + 1][rr] = bv.y; Bs[cc + 2][rr] = bv.z; Bs[cc + 3][rr] = bv.w;
        }
        __syncthreads();
        for (int kk = 0; kk < 64; ++kk) {
            float a[4];
            #pragma unroll
            for (int i = 0; i < 4; ++i) a[i] = As[ty + 16 * i][kk];
            float4 b4 = *(const float4*)(&Bs[kk][tx * 4]);
            #pragma unroll
            for (int i = 0; i < 4; ++i) {
                acc[i][0] += a[i] * b4.x; acc[i][1] += a[i] * b4.y;
                acc[i][2] += a[i] * b4.z; acc[i][3] += a[i] * b4.w;
            }
        }
        __syncthreads();
    }
    #pragma unroll
    for (int i = 0; i < 4; ++i) {
        int m = m0 + ty + 16 * i, n = n0 + tx * 4;
        float4 o;
        if (biasPerM) {
            float bm = bias[m];
            o.x = acc[i][0] + bm; o.y = acc[i][1] + bm; o.z = acc[i][2] + bm; o.w = acc[i][3] + bm;
        } else {
            o.x = acc[i][0] + bias[n]; o.y = acc[i][1] + bias[n + 1];
            o.z = acc[i][2] + bias[n + 2]; o.w = acc[i][3] + bias[n + 3];
        }
        *(float4*)(Cmat + (size_t)m * ldc + n) = o;
    }
}

// ---------------------------------------------------------- softmax q (over D)
__global__ __launch_bounds__(256) void softmax_q(float* __restrict__ q) {
    int t = threadIdx.x;
    int chunk = blockIdx.x * 4 + (t >> 6);
    int lane = t & 63;
    float* p = q + (size_t)chunk * 64;
    float v = p[lane];
    float m = v;
    for (int o = 32; o; o >>= 1) m = fmaxf(m, __shfl_xor(m, o));
    float e = expf(v - m);
    float s = e;
    for (int o = 32; o; o >>= 1) s += __shfl_xor(s, o);
    p[lane] = e / s * 0.125f;
}

// ------------------------------------------- softmax k (over C), emit bf16 too
__global__ __launch_bounds__(256) void softmax_k(float* __restrict__ kT,
                                                 unsigned short* __restrict__ kbf) {
    __shared__ float red[256];
    int j = blockIdx.x, t = threadIdx.x;
    float* row = kT + (size_t)j * C_;
    float vals[8];
    float mx = -1e30f;
    #pragma unroll
    for (int i = 0; i < 8; ++i) { vals[i] = row[t + 256 * i]; mx = fmaxf(mx, vals[i]); }
    red[t] = mx; __syncthreads();
    for (int s = 128; s; s >>= 1) { if (t < s) red[t] = fmaxf(red[t], red[t + s]); __syncthreads(); }
    mx = red[0]; __syncthreads();
    float sum = 0.f;
    #pragma unroll
    for (int i = 0; i < 8; ++i) { vals[i] = expf(vals[i] - mx); sum += vals[i]; }
    red[t] = sum; __syncthreads();
    for (int s = 128; s; s >>= 1) { if (t < s) red[t] += red[t + s]; __syncthreads(); }
    float inv = 1.0f / red[0];
    #pragma unroll
    for (int i = 0; i < 8; ++i) {
        float v = vals[i] * inv;
        row[t + 256 * i] = v;
        kbf[(size_t)j * C_ + t + 256 * i] = f2bf(v);
    }
}

// ---- T[b][j][e] = sum_c ksm[j][c] * x[b][c][e] : bf16 MFMA NT, 128x128 tile
// A = kbf[j=512][c=2048] bf16 row-major; B = xT[b][e=512][c=2048] bf16.
__global__ __launch_bounds__(256) void t_gemm(const unsigned short* __restrict__ Abf,
                                              const unsigned short* __restrict__ xT,
                                              float* __restrict__ Tout) {
    __shared__ __align__(16) unsigned short As[128 * 32];  // no padding (gld_lds)
    __shared__ __align__(16) unsigned short Bs[128 * 32];
    const int b = blockIdx.z;
    const unsigned short* Bg = xT + (size_t)b * CE;  // 512*2048 shorts
    const int m0 = blockIdx.y * 128, n0 = blockIdx.x * 128;
    const int t = threadIdx.x, lane = t & 63, w = t >> 6;
    const int wm = (w >> 1) * 64, wn = (w & 1) * 64;
    const int l15 = lane & 15, quad = lane >> 4;
    const int srow = t >> 2, sseg = (t & 3) * 8;  // stage: row, 8-short segment

    f32x4 acc[4][4];
    #pragma unroll
    for (int i = 0; i < 4; ++i)
        #pragma unroll
        for (int j = 0; j < 4; ++j) acc[i][j] = (f32x4){0.f, 0.f, 0.f, 0.f};

    for (int k0 = 0; k0 < C_; k0 += 32) {
        gld_lds16(Abf + (size_t)(m0 + srow) * C_ + k0 + sseg,        &As[srow * 32 + sseg]);
        gld_lds16(Abf + (size_t)(m0 + 64 + srow) * C_ + k0 + sseg,   &As[(64 + srow) * 32 + sseg]);
        gld_lds16(Bg  + (size_t)(n0 + srow) * C_ + k0 + sseg,        &Bs[srow * 32 + sseg]);
        gld_lds16(Bg  + (size_t)(n0 + 64 + srow) * C_ + k0 + sseg,   &Bs[(64 + srow) * 32 + sseg]);
        __syncthreads();
        bf16x8 af[4], bfr[4];
        #pragma unroll
        for (int mi = 0; mi < 4; ++mi)
            af[mi] = *(const bf16x8*)(&As[(wm + mi * 16 + l15) * 32 + quad * 8]);
        #pragma unroll
        for (int ni = 0; ni < 4; ++ni)
            bfr[ni] = *(const bf16x8*)(&Bs[(wn + ni * 16 + l15) * 32 + quad * 8]);
        #pragma unroll
        for (int mi = 0; mi < 4; ++mi)
            #pragma unroll
            for (int ni = 0; ni < 4; ++ni)
                acc[mi][ni] = __builtin_amdgcn_mfma_f32_16x16x32_bf16(
                    af[mi], bfr[ni], acc[mi][ni], 0, 0, 0);
        __syncthreads();
    }
    float* To = Tout + (size_t)b * 262144;
    #pragma unroll
    for (int mi = 0; mi < 4; ++mi)
        #pragma unroll
        for (int ni = 0; ni < 4; ++ni)
            #pragma unroll
            for (int r = 0; r < 4; ++r) {
                int m = m0 + wm + mi * 16 + quad * 4 + r;
                int n = n0 + wn + ni * 16 + l15;
                To[(size_t)m * 512 + n] = acc[mi][ni][r];
            }
}

// ------------------- ctx[b,h] = T[b,h] @ Wv_h^T + bv  (64x64 out, K=512, NT)
__global__ __launch_bounds__(256) void ctx_kernel(const float* __restrict__ T,
                                                  const float* __restrict__ Wv,
                                                  const float* __restrict__ bv,
                                                  float* __restrict__ ctx) {
    __shared__ float As[64][65];
    __shared__ float Bs[64][65];  // transposed: Bs[k][e']
    int z = blockIdx.x, b = z >> 3, h = z & 7;
    const float* A = T + (size_t)b * 262144 + (size_t)h * 64 * 512;
    const float* B = Wv + (size_t)h * 64 * 512;
    int t = threadIdx.x, tx = t & 15, ty = t >> 4;
    float acc[4][4] = {};
    for (int k0 = 0; k0 < 512; k0 += 64) {
        #pragma unroll
        for (int i = 0; i < 4; ++i) {
            int rr = ty + i * 16, cc = tx * 4;
            float4 av = *(const float4*)(A + (size_t)rr * 512 + k0 + cc);
            As[rr][cc] = av.x; As[rr][cc + 1] = av.y; As[rr][cc + 2] = av.z; As[rr][cc + 3] = av.w;
            float4 bvv = *(const float4*)(B + (size_t)rr * 512 + k0 + cc);
            Bs[cc][rr] = bvv.x; Bs[cc + 1][rr] = bvv.y; Bs[cc + 2][rr] = bvv.z; Bs[cc + 3][rr] = bvv.w;
        }
        __syncthreads();
        for (int kk = 0; kk < 64; ++kk) {
            float a[4];
            #pragma unroll
            for (int i = 0; i < 4; ++i) a[i] = As[ty + 16 * i][kk];
            float4 b4 = *(const float4*)(&Bs[kk][tx * 4]);
            #pragma unroll
            for (int i = 0; i < 4; ++i) {
                acc[i][0] += a[i] * b4.x; acc[i][1] += a[i] * b4.y;
                acc[i][2] += a[i] * b4.z; acc[i][3] += a[i] * b4.w;
            }
        }
        __syncthreads();
    }
    #pragma unroll
    for (int i = 0; i < 4; ++i) {
        int d = ty + 16 * i, e = tx * 4;
        float4 o;
        o.x = acc[i][0] + bv[h * 64 + e];     o.y = acc[i][1] + bv[h * 64 + e + 1];
        o.z = acc[i][2] + bv[h * 64 + e + 2]; o.w = acc[i][3] + bv[h * 64 + e + 3];
        *(float4*)(ctx + (size_t)z * 4096 + d * 64 + e) = o;
    }
}

// ---------------- out[b, n, h*64+e] = q[n, h*64+d] @ ctx[b,h][d][e]  (K=64)
__global__ __launch_bounds__(256) void out_kernel(const float* __restrict__ q,
                                                  const float* __restrict__ ctx,
                                                  float* __restrict__ outp) {
    __shared__ float As[64][65];  // [n][d]
    __shared__ float Bs[64][65];  // [d][e]
    int z = blockIdx.z, b = z >> 3, h = z & 7;
    int m0 = blockIdx.y * 64;
    int t = threadIdx.x, tx = t & 15, ty = t >> 4;
    #pragma unroll
    for (int i = 0; i < 4; ++i) {
        int rr = ty + i * 16, cc = tx * 4;
        float4 av = *(const float4*)(q + (size_t)(m0 + rr) * 512 + h * 64 + cc);
        As[rr][cc] = av.x; As[rr][cc + 1] = av.y; As[rr][cc + 2] = av.z; As[rr][cc + 3] = av.w;
        float4 bvv = *(const float4*)(ctx + (size_t)z * 4096 + rr * 64 + cc);
        Bs[rr][cc] = bvv.x; Bs[rr][cc + 1] = bvv.y; Bs[rr][cc + 2] = bvv.z; Bs[rr][cc + 3] = bvv.w;
    }
    __syncthreads();
    float acc[4][4] = {};
    for (int kk = 0; kk < 64; ++kk) {
        float a[4];
        #pragma unroll
        for (int i = 0; i < 4; ++i) a[i] = As[ty + 16 * i][kk];
        float4 b4 = *(const float4*)(&Bs[kk][tx * 4]);
        #pragma unroll
        for (int i = 0; i < 4; ++i) {
            acc[i][0] += a[i] * b4.x; acc[i][1] += a[i] * b4.y;
            acc[i][2] += a[i] * b4.z; acc[i][3] += a[i] * b4.w;
        }
    }
    #pragma unroll
    for (int i = 0; i < 4; ++i) {
        int n = m0 + ty + 16 * i, e = tx * 4;
        float4 o; o.x = acc[i][0]; o.y = acc[i][1]; o.z = acc[i][2]; o.w = acc[i][3];
        *(float4*)(outp + ((size_t)b * C_ + n) * E_ + h * 64 + e) = o;
    }
}

// ----------------------------- attn[h][n][m] = q[n,h:] . kT[h:][m]  (K=64)
__global__ __launch_bounds__(256) void attn_kernel(const float* __restrict__ q,
                                                   const float* __restrict__ kT,
                                                   float* __restrict__ attn) {
    __shared__ float As[64][65];  // [n][d]
    __shared__ float Bs[64][65];  // [d][m]
    int h = blockIdx.z;
    int n0 = blockIdx.y * 64, m0 = blockIdx.x * 64;
    int t = threadIdx.x, tx = t & 15, ty = t >> 4;
    #pragma unroll
    for (int i = 0; i < 4; ++i) {
        int rr = ty + i * 16, cc = tx * 4;
        float4 av = *(const float4*)(q + (size_t)(n0 + rr) * 512 + h * 64 + cc);
        As[rr][cc] = av.x; As[rr][cc + 1] = av.y; As[rr][cc + 2] = av.z; As[rr][cc + 3] = av.w;
        float4 bvv = *(const float4*)(kT + (size_t)(h * 64 + rr) * C_ + m0 + cc);
        Bs[rr][cc] = bvv.x; Bs[rr][cc + 1] = bvv.y; Bs[rr][cc + 2] = bvv.z; Bs[rr][cc + 3] = bvv.w;
    }
    __syncthreads();
    float acc[4][4] = {};
    for (int kk = 0; kk < 64; ++kk) {
        float a[4];
        #pragma unroll
        for (int i = 0; i < 4; ++i) a[i] = As[ty + 16 * i][kk];
        float4 b4 = *(const float4*)(&Bs[kk][tx * 4]);
        #pragma unroll
        for (int i = 0; i < 4; ++i) {
            acc[i][0] += a[i] * b4.x; acc[i][1] += a[i] * b4.y;
            acc[i][2] += a[i] * b4.z; acc[i][3] += a[i] * b4.w;
        }
    }
    #pragma unroll
    for (int i = 0; i < 4; ++i) {
        int n = n0 + ty + 16 * i, m = m0 + tx * 4;
        float4 o; o.x = acc[i][0]; o.y = acc[i][1]; o.z = acc[i][2]; o.w = acc[i][3];
        *(float4*)(attn + (size_t)h * C_ * C_ + (size_t)n * C_ + m) = o;
    }
}

extern "C" void kernel_launch(void* const* d_in, const int* in_sizes, int n_in,
                              void* d_out, int out_size, void* d_ws, size_t ws_size,
                              hipStream_t stream) {
    const float* x  = (const float*)d_in[0];
    const float* Wq = (const float*)d_in[1];
    const float* bq = (const float*)d_in[2];
    const float* Wk = (const float*)d_in[3];
    const float* bk = (const float*)d_in[4];
    const float* Wv = (const float*)d_in[5];
    const float* bv = (const float*)d_in[6];
    float* out = (float*)d_out;

    float* ws = (float*)d_ws;
    float* xbar = ws;                                       // 1,048,576 fl
    float* qsm  = ws + 1048576;                             // 1,048,576 fl
    float* kT   = ws + 2097152;                             // 1,048,576 fl [E][C]
    unsigned short* kbf = (unsigned short*)(ws + 3145728);  // 1,048,576 us
    float* ctx  = ws + 3670016;                             // 2,097,152 fl

    unsigned short* xTbf = (unsigned short*)d_out;          // 67.1M shorts in out region (dead before out_kernel)
    float* Tb = out + OUT_ELEMS;                            // T in attn region (dead before attn_kernel)

    prep<<<dim3(32, 8), 256, 0, stream>>>(x, xbar, xTbf);
    gemm_nt<<<dim3(8, 32), 256, 0, stream>>>(xbar, 512, Wq, 512, qsm, 512, 512, bq, 0);
    gemm_nt<<<dim3(32, 8), 256, 0, stream>>>(Wk, 512, xbar, 512, kT, 2048, 512, bk, 1);
    softmax_q<<<4096, 256, 0, stream>>>(qsm);
    softmax_k<<<512, 256, 0, stream>>>(kT, kbf);
    t_gemm<<<dim3(4, 4, 64), 256, 0, stream>>>(kbf, xTbf, Tb);
    ctx_kernel<<<512, 256, 0, stream>>>(Tb, Wv, bv, ctx);
    out_kernel<<<dim3(1, 32, 512), 256, 0, stream>>>(qsm, ctx, out);
    attn_kernel<<<dim3(32, 32, 8), 256, 0, stream>>>(qsm, kT, out + OUT_ELEMS);
}